// Round 8
// baseline (7165.973 us; speedup 1.0000x reference)
//
#include <hip/hip_runtime.h>
#include <hip/hip_bf16.h>
#include <cstddef>

// ---------------------------------------------------------------- constants
#define B_      4
#define S_      4096
#define D_      1024
#define NH_     8
#define HD_     64
#define STATE_  512           // NH_*HD_
#define PROJ_   2048          // 4*STATE_
#define ROWS_   16384         // B_*S_

typedef float f32x4 __attribute__((ext_vector_type(4)));
typedef __bf16 bf16x8 __attribute__((ext_vector_type(8)));
typedef _Float16 f16x2 __attribute__((ext_vector_type(2)));

// ---------------------------------------------------------------- helpers
__device__ __forceinline__ unsigned short bfbits(float f) {
    __hip_bfloat16 h = __float2bfloat16(f);
    return __builtin_bit_cast(unsigned short, h);
}

__device__ __forceinline__ float b2f(unsigned short u) {
    union { unsigned int i; float f; } v;
    v.i = ((unsigned int)u) << 16;
    return v.f;
}

__device__ __forceinline__ float fast_sigmoid(float x) {
    return __builtin_amdgcn_rcpf(1.0f + __expf(-x));
}

__device__ __forceinline__ float fast_tanh(float x) {
    return 1.0f - 2.0f * __builtin_amdgcn_rcpf(__expf(2.0f * x) + 1.0f);
}

__device__ __forceinline__ void async_copy16(void* lds, const void* g) {
    __builtin_amdgcn_global_load_lds(
        (const __attribute__((address_space(1))) unsigned int*)g,
        (__attribute__((address_space(3))) unsigned int*)lds,
        16, 0, 0);
}

// pack two fp32 into f16x2 bits (v_cvt_pkrtz_f16_f32)
__device__ __forceinline__ unsigned int pkf16(float a, float b) {
    auto h = __builtin_amdgcn_cvt_pkrtz(a, b);   // __fp16 ext_vector(2)
    return __builtin_bit_cast(unsigned int, h);
}

__device__ __forceinline__ f16x2 u2h(unsigned int u) {
    return __builtin_bit_cast(f16x2, u);
}

// broadcast-read a u32 (f16-pair) from lane `lane` (compile-time const)
__device__ __forceinline__ unsigned int rl_u32(unsigned int v, int lane) {
    return (unsigned int)__builtin_amdgcn_readlane((int)v, lane);
}

__device__ __forceinline__ float fdot2f(f16x2 a, f16x2 b, float c) {
    return __builtin_amdgcn_fdot2(a, b, c, false);   // proven numerics (r0-r2, r5, r7)
}

// pack (h[2p], h[2p+1]) as f16x2: lane k pairs with lane k^1 via DPP quad_perm
__device__ __forceinline__ unsigned int pack_pair(float v, bool oddlane) {
    int vb = __builtin_bit_cast(int, v);
    int pb = __builtin_amdgcn_mov_dpp(vb, 0xB1, 0xF, 0xF, true);  // lane ^ 1
    float p = __builtin_bit_cast(float, pb);
    float lo = oddlane ? p : v;
    float hi = oddlane ? v : p;
    return pkf16(lo, hi);
}

// ---------------------------------------------------------------- fp32 -> bf16 convert
__global__ __launch_bounds__(256) void f2bf(const float* __restrict__ in,
                                            unsigned short* __restrict__ out, int n4) {
    int i = blockIdx.x * 256 + threadIdx.x;
    if (i < n4) {
        float4 v = ((const float4*)in)[i];
        ushort4 o;
        o.x = bfbits(v.x); o.y = bfbits(v.y); o.z = bfbits(v.z); o.w = bfbits(v.w);
        ((ushort4*)out)[i] = o;
    }
}

// ---------------------------------------------------------------- GEMM  C[M,N] = A[M,K] * B[N,K]^T
__device__ __forceinline__ void store_out(float* p, float v) { *p = v; }
__device__ __forceinline__ void store_out(__hip_bfloat16* p, float v) { *p = __float2bfloat16(v); }

template <typename OutT>
__global__ __launch_bounds__(256, 1) void gemm_bt(const unsigned short* __restrict__ A,
                                                  const unsigned short* __restrict__ Bm,
                                                  OutT* __restrict__ C,
                                                  int M, int N, int K) {
    __shared__ __align__(16) unsigned short As[128 * 32];
    __shared__ __align__(16) unsigned short Bs[128 * 32];
    const int tid  = threadIdx.x;
    const int lane = tid & 63;
    const int w    = tid >> 6;
    const int wm   = w >> 1;
    const int wn   = w & 1;
    const int l16  = lane & 15;
    const int quad = lane >> 4;
    const int m0 = blockIdx.y * 128;
    const int n0 = blockIdx.x * 128;

    f32x4 acc[4][4] = {};

    const int off0 = w * 1024 + lane * 16;
    const int off1 = (w + 4) * 1024 + lane * 16;
    const int r0 = off0 >> 6, cb0 = off0 & 63;
    const int r1 = off1 >> 6, cb1 = off1 & 63;
    char* lA0 = (char*)As + w * 1024;
    char* lA1 = (char*)As + (w + 4) * 1024;
    char* lB0 = (char*)Bs + w * 1024;
    char* lB1 = (char*)Bs + (w + 4) * 1024;
    const size_t Kb = (size_t)K * 2;

    for (int k0 = 0; k0 < K; k0 += 32) {
        const char* a0 = (const char*)A + (size_t)(m0 + r0) * Kb + (size_t)k0 * 2 + cb0;
        const char* a1 = (const char*)A + (size_t)(m0 + r1) * Kb + (size_t)k0 * 2 + cb1;
        const char* b0 = (const char*)Bm + (size_t)(n0 + r0) * Kb + (size_t)k0 * 2 + cb0;
        const char* b1 = (const char*)Bm + (size_t)(n0 + r1) * Kb + (size_t)k0 * 2 + cb1;
        async_copy16(lA0, a0);
        async_copy16(lA1, a1);
        async_copy16(lB0, b0);
        async_copy16(lB1, b1);
        __syncthreads();

        bf16x8 af[4], bf[4];
#pragma unroll
        for (int mt = 0; mt < 4; ++mt) {
            int r = wm * 64 + mt * 16 + l16;
            af[mt] = *(const bf16x8*)(&As[r * 32 + quad * 8]);
        }
#pragma unroll
        for (int nt = 0; nt < 4; ++nt) {
            int r = wn * 64 + nt * 16 + l16;
            bf[nt] = *(const bf16x8*)(&Bs[r * 32 + quad * 8]);
        }
#pragma unroll
        for (int mt = 0; mt < 4; ++mt)
#pragma unroll
            for (int nt = 0; nt < 4; ++nt)
                acc[mt][nt] = __builtin_amdgcn_mfma_f32_16x16x32_bf16(af[mt], bf[nt], acc[mt][nt], 0, 0, 0);
        __syncthreads();
    }

#pragma unroll
    for (int mt = 0; mt < 4; ++mt) {
#pragma unroll
        for (int nt = 0; nt < 4; ++nt) {
            const int col = n0 + wn * 64 + nt * 16 + l16;
            const int row = m0 + wm * 64 + mt * 16 + quad * 4;
#pragma unroll
            for (int rg = 0; rg < 4; ++rg)
                store_out(&C[(size_t)(row + rg) * N + col], acc[mt][nt][rg]);
        }
    }
}

// ---------------------------------------------------------------- proj -> scan-friendly layout
// sc[((b*8+n)*S_ + t)*64 + k] = {xi, xf, xr, g} at channel c = n*64+k
__global__ __launch_bounds__(256) void transpose_scan(const unsigned short* __restrict__ proj,
                                                      ushort4* __restrict__ sc) {
    const int idx = blockIdx.x * 256 + threadIdx.x;   // 0 .. ROWS_*512-1
    const int c   = idx & 511;
    const int row = idx >> 9;
    const int b = row >> 12, t = row & 4095;
    const int n = c >> 6, kk = c & 63;
    const unsigned short* src = proj + (size_t)row * PROJ_ + c;
    ushort4 v;
    v.x = src[0];
    v.y = src[512];
    v.z = src[1024];
    v.w = src[1536];
    sc[((size_t)(b * 8 + n) * S_ + t) * 64 + kk] = v;
}

// ---------------------------------------------------------------- recurrent scan
// ONE wave per HEAD handling all 4 BATCHES (8 blocks x 64 thr). The scan is
// stall-bound (r7: 1063 cyc/step for ~220 instrs = 4.8 cyc/instr, ~600 cyc of
// dependency stalls a single in-order wave can't fill). The 4 batches of a
// head are independent streams sharing the SAME weights (96 VGPRs, once!);
// folding them into one wave puts independent work between dependent
// instructions in program order -- per-stream-equivalent cost ~450-500 cyc.
// r7's proven pattern kept: batched readlanes -> sched_barrier -> dot block,
// with TWO 32-entry SGPR buffers reused across batch pairs (SGPR budget).
// Per-stream op sequence/associations identical to r7 => absmax 0.015625.

#define SB __builtin_amdgcn_sched_barrier(0);

#define DECODE(b, T, V)                                                        \
    const float xf_##b = b2f(V.y);                                             \
    const float xr_##b = b2f(V.z);                                             \
    const float g_##b  = b2f(V.w);                                             \
    float xc_##b;                                                              \
    {                                                                          \
        const float xi_raw = b2f(V.x);                                         \
        const int tn = ((T) + 2 < S_) ? (T) + 2 : S_ - 1;                      \
        V = pin_##b[(size_t)tn * 64];                                          \
        xc_##b = fmaf(cw3, xi_raw,                                             \
                 fmaf(cw2, xm1_##b, fmaf(cw1, xm2_##b, cw0 * xm3_##b)));       \
        xm3_##b = xm2_##b; xm2_##b = xm1_##b; xm1_##b = xi_raw;                \
    }                                                                          \
    const float xiv_##b = xc_##b * fast_sigmoid(xc_##b);                       \
    const float gsv_##b = g_##b * fast_sigmoid(g_##b);

#define RLB(arr, src)                                                          \
    _Pragma("unroll")                                                          \
    for (int p = 0; p < 32; ++p) arr[p] = rl_u32(src, 2 * p);

#define FRD(b, arr)                                                            \
    float fa_##b[4] = {xf_##b, 0.f, 0.f, 0.f};                                 \
    float ra_##b[4] = {xr_##b, 0.f, 0.f, 0.f};                                 \
    _Pragma("unroll")                                                          \
    for (int p = 0; p < 32; ++p) {                                             \
        fa_##b[p & 3] = fdot2f(u2h(arr[p]), u2h(Wf2[p]), fa_##b[p & 3]);       \
        ra_##b[p & 3] = fdot2f(u2h(arr[p]), u2h(Wr2[p]), ra_##b[p & 3]);       \
    }

#define GAT(b)                                                                 \
    const float fv_##b = fast_sigmoid((fa_##b[0] + fa_##b[1]) +                \
                                      (fa_##b[2] + fa_##b[3]));                \
    const float rv_##b = fast_sigmoid((ra_##b[0] + ra_##b[1]) +                \
                                      (ra_##b[2] + ra_##b[3]));                \
    const unsigned int hr_##b = pack_pair(h_##b * rv_##b, oddlane);

#define ZD(b, arr)                                                             \
    float za_##b[4] = {xiv_##b, 0.f, 0.f, 0.f};                                \
    _Pragma("unroll")                                                          \
    for (int p = 0; p < 32; ++p)                                               \
        za_##b[p & 3] = fdot2f(u2h(arr[p]), u2h(Wz2[p]), za_##b[p & 3]);

#define UPD(b, T)                                                              \
    {                                                                          \
        const float zv = fast_tanh((za_##b[0] + za_##b[1]) +                   \
                                   (za_##b[2] + za_##b[3]));                   \
        const float hn = fmaf(fv_##b, h_##b - zv, zv);                         \
        h_##b  = hn;                                                           \
        hp_##b = pack_pair(hn, oddlane);                                       \
        yout_##b[(size_t)(T) * STATE_] = hn * gsv_##b;                         \
    }

#define STEP4(T, V0, V1, V2, V3)                                               \
    {                                                                          \
        DECODE(0, T, V0) DECODE(1, T, V1) DECODE(2, T, V2) DECODE(3, T, V3)    \
        unsigned int hsA[32], hsB[32];                                         \
        RLB(hsA, hp_0) RLB(hsB, hp_1) SB                                       \
        FRD(0, hsA) FRD(1, hsB) SB                                             \
        RLB(hsA, hp_2) RLB(hsB, hp_3) SB                                       \
        GAT(0) GAT(1)                                                          \
        FRD(2, hsA) FRD(3, hsB) SB                                             \
        GAT(2) GAT(3)                                                          \
        RLB(hsA, hr_0) RLB(hsB, hr_1) SB                                       \
        ZD(0, hsA) ZD(1, hsB) SB                                               \
        RLB(hsA, hr_2) RLB(hsB, hr_3) SB                                       \
        ZD(2, hsA) ZD(3, hsB)                                                  \
        UPD(0, T) UPD(1, T) UPD(2, T) UPD(3, T)                                \
    }

__global__ __launch_bounds__(64)
__attribute__((amdgpu_waves_per_eu(1, 1)))
void scan_kernel(
    const ushort4* __restrict__ scanin,        // ((b*8+n)*S + t)*64 + k -> {xi,xf,xr,g}
    const float* __restrict__ conv_w,          // (512, 4)
    const float* __restrict__ sw,              // (24, 64, 64)
    float* __restrict__ y)                     // (ROWS_, 512): h * silu(g)
{
    const int n = blockIdx.x;           // 0..7 head
    const int k = threadIdx.x;          // 0..63 output column
    const int c = n * HD_ + k;
    const bool oddlane = (k & 1) != 0;

    // W columns packed as f16 j-pairs: thread k holds column k (shared by all batches)
    unsigned int Wz2[32], Wf2[32], Wr2[32];
    {
        const float* wz = sw + (size_t)n * 4096 + k;
        const float* wf = wz + 8 * 4096;
        const float* wr = wz + 16 * 4096;
#pragma unroll
        for (int jp = 0; jp < 32; ++jp) {
            Wz2[jp] = pkf16(wz[(2 * jp) * 64], wz[(2 * jp + 1) * 64]);
            Wf2[jp] = pkf16(wf[(2 * jp) * 64], wf[(2 * jp + 1) * 64]);
            Wr2[jp] = pkf16(wr[(2 * jp) * 64], wr[(2 * jp + 1) * 64]);
        }
    }
    const float cw0 = conv_w[c * 4 + 0];
    const float cw1 = conv_w[c * 4 + 1];
    const float cw2 = conv_w[c * 4 + 2];
    const float cw3 = conv_w[c * 4 + 3];

    float h_0 = 0.f, h_1 = 0.f, h_2 = 0.f, h_3 = 0.f;
    unsigned int hp_0 = 0, hp_1 = 0, hp_2 = 0, hp_3 = 0;
    float xm1_0 = 0.f, xm2_0 = 0.f, xm3_0 = 0.f;
    float xm1_1 = 0.f, xm2_1 = 0.f, xm3_1 = 0.f;
    float xm1_2 = 0.f, xm2_2 = 0.f, xm3_2 = 0.f;
    float xm1_3 = 0.f, xm2_3 = 0.f, xm3_3 = 0.f;

    const ushort4* pin_0 = scanin + (size_t)(0 * 8 + n) * S_ * 64 + k;
    const ushort4* pin_1 = scanin + (size_t)(1 * 8 + n) * S_ * 64 + k;
    const ushort4* pin_2 = scanin + (size_t)(2 * 8 + n) * S_ * 64 + k;
    const ushort4* pin_3 = scanin + (size_t)(3 * 8 + n) * S_ * 64 + k;
    float* yout_0 = y + (size_t)0 * S_ * STATE_ + c;
    float* yout_1 = y + (size_t)1 * S_ * STATE_ + c;
    float* yout_2 = y + (size_t)2 * S_ * STATE_ + c;
    float* yout_3 = y + (size_t)3 * S_ * STATE_ + c;

    ushort4 pA0 = pin_0[0], pB0 = pin_0[64];
    ushort4 pA1 = pin_1[0], pB1 = pin_1[64];
    ushort4 pA2 = pin_2[0], pB2 = pin_2[64];
    ushort4 pA3 = pin_3[0], pB3 = pin_3[64];

    for (int t = 0; t < S_; t += 2) {
        STEP4(t,     pA0, pA1, pA2, pA3);
        STEP4(t + 1, pB0, pB1, pB2, pB3);
    }
}

// ---------------------------------------------------------------- RMSNorm + bf16 cast
__global__ __launch_bounds__(128) void rmsnorm_bf16(const float* __restrict__ y,
                                                    const float* __restrict__ nw,
                                                    unsigned short* __restrict__ out) {
    const int row = blockIdx.x;
    const int t   = threadIdx.x;
    const float4 v = ((const float4*)(y + (size_t)row * STATE_))[t];
    float ss = fmaf(v.x, v.x, fmaf(v.y, v.y, fmaf(v.z, v.z, v.w * v.w)));
#pragma unroll
    for (int off = 32; off > 0; off >>= 1) ss += __shfl_xor(ss, off, 64);
    __shared__ float wred[2];
    if ((t & 63) == 0) wred[t >> 6] = ss;
    __syncthreads();
    const float tot   = wred[0] + wred[1];
    const float scale = rsqrtf(tot * (1.0f / (float)STATE_) + 1e-6f);
    const float4 w4 = ((const float4*)nw)[t];
    ushort4 o;
    o.x = bfbits(v.x * scale * w4.x);
    o.y = bfbits(v.y * scale * w4.y);
    o.z = bfbits(v.z * scale * w4.z);
    o.w = bfbits(v.w * scale * w4.w);
    ((ushort4*)out)[(size_t)row * (STATE_ / 4) + t] = o;
}

// ---------------------------------------------------------------- launcher
extern "C" void kernel_launch(void* const* d_in, const int* in_sizes, int n_in,
                              void* d_out, int out_size, void* d_ws, size_t ws_size,
                              hipStream_t stream) {
    const float* x      = (const float*)d_in[0];
    const float* w_in   = (const float*)d_in[1];
    const float* conv_w = (const float*)d_in[2];
    const float* sw     = (const float*)d_in[3];
    const float* norm_w = (const float*)d_in[4];
    const float* w_out  = (const float*)d_in[5];
    float* out = (float*)d_out;                    // (4,4096,1024) fp32 = 64 MiB

    // workspace layout (bytes):
    //   [0,        33554432)  xbf (bf16)      -- reused as y fp32 after GEMM1
    //   [33554432, 37748736)  w_inbf
    //   [37748736, 38797312)  w_outbf
    //   [38797312, 105906176) scanin (ushort4) -- reused as ybf after scan
    // projbf (16384x2048 bf16 = 64 MiB) lives in d_out until transpose_scan reads it.
    char* ws = (char*)d_ws;
    unsigned short* xbf     = (unsigned short*)(ws + 0);
    unsigned short* w_inbf  = (unsigned short*)(ws + 33554432);
    unsigned short* w_outbf = (unsigned short*)(ws + 37748736);
    ushort4*        scanin  = (ushort4*)(ws + 38797312);
    float*          yf      = (float*)(ws + 0);
    unsigned short* ybf     = (unsigned short*)(ws + 38797312);
    unsigned short* projbf  = (unsigned short*)d_out;   // scratch inside d_out

    // 1) fp32 -> bf16 converts
    f2bf<<<(ROWS_ * D_ / 4 + 255) / 256, 256, 0, stream>>>(x, xbf, ROWS_ * D_ / 4);
    f2bf<<<(PROJ_ * D_ / 4 + 255) / 256, 256, 0, stream>>>(w_in, w_inbf, PROJ_ * D_ / 4);
    f2bf<<<(D_ * STATE_ / 4 + 255) / 256, 256, 0, stream>>>(w_out, w_outbf, D_ * STATE_ / 4);

    // 2) proj = x @ w_in^T -> bf16 (into d_out scratch)
    gemm_bt<__hip_bfloat16><<<dim3(PROJ_ / 128, ROWS_ / 128), 256, 0, stream>>>(
        xbf, w_inbf, (__hip_bfloat16*)projbf, ROWS_, PROJ_, D_);

    // 3) rearrange proj for the scan (1 coalesced b64 load per step per lane)
    transpose_scan<<<ROWS_ * 512 / 256, 256, 0, stream>>>(projbf, scanin);

    // 4) recurrence (conv+silu+scan+silu(g) fused), writes y fp32
    //    8 blocks x 1 wave: one wave per head, 4 batches folded per wave
    scan_kernel<<<8, 64, 0, stream>>>(scanin, conv_w, sw, yf);

    // 5) RMSNorm + bf16 cast
    rmsnorm_bf16<<<ROWS_, 128, 0, stream>>>(yf, norm_w, ybf);

    // 6) out = y_norm @ w_out^T (overwrites the projbf scratch)
    gemm_bt<float><<<dim3(D_ / 128, ROWS_ / 128), 256, 0, stream>>>(
        ybf, w_outbf, out, ROWS_, D_, STATE_);
}

// Round 9
// 2136.983 us; speedup vs baseline: 3.3533x; 3.3533x over previous
//
#include <hip/hip_runtime.h>
#include <hip/hip_bf16.h>
#include <cstddef>

// ---------------------------------------------------------------- constants
#define B_      4
#define S_      4096
#define D_      1024
#define NH_     8
#define HD_     64
#define STATE_  512           // NH_*HD_
#define PROJ_   2048          // 4*STATE_
#define ROWS_   16384         // B_*S_

typedef float f32x4 __attribute__((ext_vector_type(4)));
typedef __bf16 bf16x8 __attribute__((ext_vector_type(8)));
typedef _Float16 f16x2 __attribute__((ext_vector_type(2)));

// ---------------------------------------------------------------- helpers
__device__ __forceinline__ unsigned short bfbits(float f) {
    __hip_bfloat16 h = __float2bfloat16(f);
    return __builtin_bit_cast(unsigned short, h);
}

__device__ __forceinline__ float b2f(unsigned short u) {
    union { unsigned int i; float f; } v;
    v.i = ((unsigned int)u) << 16;
    return v.f;
}

__device__ __forceinline__ float fast_sigmoid(float x) {
    return __builtin_amdgcn_rcpf(1.0f + __expf(-x));
}

__device__ __forceinline__ float fast_tanh(float x) {
    return 1.0f - 2.0f * __builtin_amdgcn_rcpf(__expf(2.0f * x) + 1.0f);
}

__device__ __forceinline__ void async_copy16(void* lds, const void* g) {
    __builtin_amdgcn_global_load_lds(
        (const __attribute__((address_space(1))) unsigned int*)g,
        (__attribute__((address_space(3))) unsigned int*)lds,
        16, 0, 0);
}

// pack two fp32 into f16x2 bits (v_cvt_pkrtz_f16_f32)
__device__ __forceinline__ unsigned int pkf16(float a, float b) {
    auto h = __builtin_amdgcn_cvt_pkrtz(a, b);   // __fp16 ext_vector(2)
    return __builtin_bit_cast(unsigned int, h);
}

__device__ __forceinline__ f16x2 u2h(unsigned int u) {
    return __builtin_bit_cast(f16x2, u);
}

__device__ __forceinline__ float fdot2f(f16x2 a, f16x2 b, float c) {
    return __builtin_amdgcn_fdot2(a, b, c, false);   // proven numerics (r0-r2, r5-r7)
}

// pack (h[2p], h[2p+1]) as f16x2: lane k pairs with lane k^1 via DPP quad_perm
__device__ __forceinline__ unsigned int pack_pair(float v, bool oddlane) {
    int vb = __builtin_bit_cast(int, v);
    int pb = __builtin_amdgcn_mov_dpp(vb, 0xB1, 0xF, 0xF, true);  // lane ^ 1
    float p = __builtin_bit_cast(float, pb);
    float lo = oddlane ? p : v;
    float hi = oddlane ? v : p;
    return pkf16(lo, hi);
}

// ---------------------------------------------------------------- fp32 -> bf16 convert
__global__ __launch_bounds__(256) void f2bf(const float* __restrict__ in,
                                            unsigned short* __restrict__ out, int n4) {
    int i = blockIdx.x * 256 + threadIdx.x;
    if (i < n4) {
        float4 v = ((const float4*)in)[i];
        ushort4 o;
        o.x = bfbits(v.x); o.y = bfbits(v.y); o.z = bfbits(v.z); o.w = bfbits(v.w);
        ((ushort4*)out)[i] = o;
    }
}

// ---------------------------------------------------------------- GEMM  C[M,N] = A[M,K] * B[N,K]^T
__device__ __forceinline__ void store_out(float* p, float v) { *p = v; }
__device__ __forceinline__ void store_out(__hip_bfloat16* p, float v) { *p = __float2bfloat16(v); }

template <typename OutT>
__global__ __launch_bounds__(256, 1) void gemm_bt(const unsigned short* __restrict__ A,
                                                  const unsigned short* __restrict__ Bm,
                                                  OutT* __restrict__ C,
                                                  int M, int N, int K) {
    __shared__ __align__(16) unsigned short As[128 * 32];
    __shared__ __align__(16) unsigned short Bs[128 * 32];
    const int tid  = threadIdx.x;
    const int lane = tid & 63;
    const int w    = tid >> 6;
    const int wm   = w >> 1;
    const int wn   = w & 1;
    const int l16  = lane & 15;
    const int quad = lane >> 4;
    const int m0 = blockIdx.y * 128;
    const int n0 = blockIdx.x * 128;

    f32x4 acc[4][4] = {};

    const int off0 = w * 1024 + lane * 16;
    const int off1 = (w + 4) * 1024 + lane * 16;
    const int r0 = off0 >> 6, cb0 = off0 & 63;
    const int r1 = off1 >> 6, cb1 = off1 & 63;
    char* lA0 = (char*)As + w * 1024;
    char* lA1 = (char*)As + (w + 4) * 1024;
    char* lB0 = (char*)Bs + w * 1024;
    char* lB1 = (char*)Bs + (w + 4) * 1024;
    const size_t Kb = (size_t)K * 2;

    for (int k0 = 0; k0 < K; k0 += 32) {
        const char* a0 = (const char*)A + (size_t)(m0 + r0) * Kb + (size_t)k0 * 2 + cb0;
        const char* a1 = (const char*)A + (size_t)(m0 + r1) * Kb + (size_t)k0 * 2 + cb1;
        const char* b0 = (const char*)Bm + (size_t)(n0 + r0) * Kb + (size_t)k0 * 2 + cb0;
        const char* b1 = (const char*)Bm + (size_t)(n0 + r1) * Kb + (size_t)k0 * 2 + cb1;
        async_copy16(lA0, a0);
        async_copy16(lA1, a1);
        async_copy16(lB0, b0);
        async_copy16(lB1, b1);
        __syncthreads();

        bf16x8 af[4], bf[4];
#pragma unroll
        for (int mt = 0; mt < 4; ++mt) {
            int r = wm * 64 + mt * 16 + l16;
            af[mt] = *(const bf16x8*)(&As[r * 32 + quad * 8]);
        }
#pragma unroll
        for (int nt = 0; nt < 4; ++nt) {
            int r = wn * 64 + nt * 16 + l16;
            bf[nt] = *(const bf16x8*)(&Bs[r * 32 + quad * 8]);
        }
#pragma unroll
        for (int mt = 0; mt < 4; ++mt)
#pragma unroll
            for (int nt = 0; nt < 4; ++nt)
                acc[mt][nt] = __builtin_amdgcn_mfma_f32_16x16x32_bf16(af[mt], bf[nt], acc[mt][nt], 0, 0, 0);
        __syncthreads();
    }

#pragma unroll
    for (int mt = 0; mt < 4; ++mt) {
#pragma unroll
        for (int nt = 0; nt < 4; ++nt) {
            const int col = n0 + wn * 64 + nt * 16 + l16;
            const int row = m0 + wm * 64 + mt * 16 + quad * 4;
#pragma unroll
            for (int rg = 0; rg < 4; ++rg)
                store_out(&C[(size_t)(row + rg) * N + col], acc[mt][nt][rg]);
        }
    }
}

// ---------------------------------------------------------------- proj -> scan-friendly layout
// sc[((b*8+n)*S_ + t)*64 + k] = {xi, xf, xr, g} at channel c = n*64+k
__global__ __launch_bounds__(256) void transpose_scan(const unsigned short* __restrict__ proj,
                                                      ushort4* __restrict__ sc) {
    const int idx = blockIdx.x * 256 + threadIdx.x;   // 0 .. ROWS_*512-1
    const int c   = idx & 511;
    const int row = idx >> 9;
    const int b = row >> 12, t = row & 4095;
    const int n = c >> 6, kk = c & 63;
    const unsigned short* src = proj + (size_t)row * PROJ_ + c;
    ushort4 v;
    v.x = src[0];
    v.y = src[512];
    v.z = src[1024];
    v.w = src[1536];
    sc[((size_t)(b * 8 + n) * S_ + t) * 64 + kk] = v;
}

// ---------------------------------------------------------------- recurrent scan
// One wave per (batch, head) (32 blocks x 64 thr; r7 structure) with the
// broadcast mechanism swapped: LDS wave-uniform ds_read_b128 instead of
// v_readlane. r8 showed the readlane path is SGPR-capacity-limited (one
// buffer max) and r7's 1063 cyc/step carries ~600 cyc unexplained by the
// issue+latency model -- attributed to the VALU->SGPR->VALU machinery of
// 64 readlanes + 96 SGPR-operand dots. Here h/hr pairs bounce through LDS
// (even-lane ds_write + 8 uniform b128 reads; operands land in VGPRs).
// h-pair read latency hides under decode/conv; only the hr bounce (~80cy)
// is exposed. Same fdot2/associations/pack bits as r7 => absmax 0.015625.
#define SCAN_STEP(T, V)                                                        \
    {                                                                          \
        const float xi_raw = b2f(V.x);                                         \
        const float xf_v   = b2f(V.y);                                         \
        const float xr_v   = b2f(V.z);                                         \
        const float g_v    = b2f(V.w);                                         \
        {   /* prefetch t+2 (clamped; tail loads unused) */                    \
            const int tn = ((T) + 2 < S_) ? (T) + 2 : S_ - 1;                  \
            V = pin[(size_t)tn * 64];                                          \
        }                                                                      \
        float xc = fmaf(cw3, xi_raw, fmaf(cw2, xm1, fmaf(cw1, xm2, cw0 * xm3)));\
        xm3 = xm2; xm2 = xm1; xm1 = xi_raw;                                    \
        const float xi_v = xc * fast_sigmoid(xc);                              \
        const float gs_v = g_v * fast_sigmoid(g_v);                            \
        const uint4 p0 = *(const uint4*)&lds_hp[0];                            \
        const uint4 p1 = *(const uint4*)&lds_hp[4];                            \
        const uint4 p2 = *(const uint4*)&lds_hp[8];                            \
        const uint4 p3 = *(const uint4*)&lds_hp[12];                           \
        const uint4 p4 = *(const uint4*)&lds_hp[16];                           \
        const uint4 p5 = *(const uint4*)&lds_hp[20];                           \
        const uint4 p6 = *(const uint4*)&lds_hp[24];                           \
        const uint4 p7 = *(const uint4*)&lds_hp[28];                           \
        float fa[4] = {xf_v, 0.f, 0.f, 0.f};                                   \
        float ra[4] = {xr_v, 0.f, 0.f, 0.f};                                   \
        DOT4(p0, 0)  DOT4(p1, 4)  DOT4(p2, 8)  DOT4(p3, 12)                    \
        DOT4(p4, 16) DOT4(p5, 20) DOT4(p6, 24) DOT4(p7, 28)                    \
        const float f_v = fast_sigmoid((fa[0] + fa[1]) + (fa[2] + fa[3]));     \
        const float r_v = fast_sigmoid((ra[0] + ra[1]) + (ra[2] + ra[3]));     \
        const unsigned int hrpk = pack_pair(h_me * r_v, oddlane);              \
        if (!oddlane) lds_hr[k >> 1] = hrpk;                                   \
        const uint4 s0 = *(const uint4*)&lds_hr[0];                            \
        const uint4 s1 = *(const uint4*)&lds_hr[4];                            \
        const uint4 s2 = *(const uint4*)&lds_hr[8];                            \
        const uint4 s3 = *(const uint4*)&lds_hr[12];                           \
        const uint4 s4 = *(const uint4*)&lds_hr[16];                           \
        const uint4 s5 = *(const uint4*)&lds_hr[20];                           \
        const uint4 s6 = *(const uint4*)&lds_hr[24];                           \
        const uint4 s7 = *(const uint4*)&lds_hr[28];                           \
        float za[4] = {xi_v, 0.f, 0.f, 0.f};                                   \
        ZDT4(s0, 0)  ZDT4(s1, 4)  ZDT4(s2, 8)  ZDT4(s3, 12)                    \
        ZDT4(s4, 16) ZDT4(s5, 20) ZDT4(s6, 24) ZDT4(s7, 28)                    \
        const float z_v = fast_tanh((za[0] + za[1]) + (za[2] + za[3]));        \
        const float hn  = fmaf(f_v, h_me - z_v, z_v);                          \
        h_me = hn;                                                             \
        const unsigned int hpk = pack_pair(hn, oddlane);                       \
        if (!oddlane) lds_hp[k >> 1] = hpk;                                    \
        yout[(size_t)(T) * STATE_] = hn * gs_v;                                \
    }

#define DOT4(Q, P)                                                             \
    fa[0] = fdot2f(u2h(Q.x), u2h(Wf2[(P)]),     fa[0]);                        \
    ra[0] = fdot2f(u2h(Q.x), u2h(Wr2[(P)]),     ra[0]);                        \
    fa[1] = fdot2f(u2h(Q.y), u2h(Wf2[(P) + 1]), fa[1]);                        \
    ra[1] = fdot2f(u2h(Q.y), u2h(Wr2[(P) + 1]), ra[1]);                        \
    fa[2] = fdot2f(u2h(Q.z), u2h(Wf2[(P) + 2]), fa[2]);                        \
    ra[2] = fdot2f(u2h(Q.z), u2h(Wr2[(P) + 2]), ra[2]);                        \
    fa[3] = fdot2f(u2h(Q.w), u2h(Wf2[(P) + 3]), fa[3]);                        \
    ra[3] = fdot2f(u2h(Q.w), u2h(Wr2[(P) + 3]), ra[3]);

#define ZDT4(Q, P)                                                             \
    za[0] = fdot2f(u2h(Q.x), u2h(Wz2[(P)]),     za[0]);                        \
    za[1] = fdot2f(u2h(Q.y), u2h(Wz2[(P) + 1]), za[1]);                        \
    za[2] = fdot2f(u2h(Q.z), u2h(Wz2[(P) + 2]), za[2]);                        \
    za[3] = fdot2f(u2h(Q.w), u2h(Wz2[(P) + 3]), za[3]);

__global__ __launch_bounds__(64)
__attribute__((amdgpu_waves_per_eu(1, 1)))
void scan_kernel(
    const ushort4* __restrict__ scanin,        // ((b*8+n)*S + t)*64 + k -> {xi,xf,xr,g}
    const float* __restrict__ conv_w,          // (512, 4)
    const float* __restrict__ sw,              // (24, 64, 64)
    float* __restrict__ y)                     // (ROWS_, 512): h * silu(g)
{
    __shared__ __align__(16) unsigned int lds_hp[32];   // h as f16 j-pairs
    __shared__ __align__(16) unsigned int lds_hr[32];   // h*r as f16 j-pairs

    const int bn = blockIdx.x;          // 0..31
    const int b  = bn >> 3;
    const int n  = bn & 7;
    const int k  = threadIdx.x;         // 0..63 output column
    const int c  = n * HD_ + k;
    const bool oddlane = (k & 1) != 0;

    // W columns packed as f16 j-pairs: thread k holds column k
    unsigned int Wz2[32], Wf2[32], Wr2[32];
    {
        const float* wz = sw + (size_t)n * 4096 + k;
        const float* wf = wz + 8 * 4096;
        const float* wr = wz + 16 * 4096;
#pragma unroll
        for (int jp = 0; jp < 32; ++jp) {
            Wz2[jp] = pkf16(wz[(2 * jp) * 64], wz[(2 * jp + 1) * 64]);
            Wf2[jp] = pkf16(wf[(2 * jp) * 64], wf[(2 * jp + 1) * 64]);
            Wr2[jp] = pkf16(wr[(2 * jp) * 64], wr[(2 * jp + 1) * 64]);
        }
    }
    const float cw0 = conv_w[c * 4 + 0];
    const float cw1 = conv_w[c * 4 + 1];
    const float cw2 = conv_w[c * 4 + 2];
    const float cw3 = conv_w[c * 4 + 3];

    float h_me = 0.0f;
    float xm1 = 0.f, xm2 = 0.f, xm3 = 0.f;

    if (!oddlane) lds_hp[k >> 1] = 0u;   // h(=0) pairs; single wave, in-order LDS

    const ushort4* pin = scanin + (size_t)bn * S_ * 64 + k;
    float* yout = y + (size_t)b * S_ * STATE_ + c;

    ushort4 aV = pin[0];
    ushort4 bV = pin[64];

    for (int t = 0; t < S_; t += 2) {
        SCAN_STEP(t,     aV);
        SCAN_STEP(t + 1, bV);
    }
}

// ---------------------------------------------------------------- RMSNorm + bf16 cast
__global__ __launch_bounds__(128) void rmsnorm_bf16(const float* __restrict__ y,
                                                    const float* __restrict__ nw,
                                                    unsigned short* __restrict__ out) {
    const int row = blockIdx.x;
    const int t   = threadIdx.x;
    const float4 v = ((const float4*)(y + (size_t)row * STATE_))[t];
    float ss = fmaf(v.x, v.x, fmaf(v.y, v.y, fmaf(v.z, v.z, v.w * v.w)));
#pragma unroll
    for (int off = 32; off > 0; off >>= 1) ss += __shfl_xor(ss, off, 64);
    __shared__ float wred[2];
    if ((t & 63) == 0) wred[t >> 6] = ss;
    __syncthreads();
    const float tot   = wred[0] + wred[1];
    const float scale = rsqrtf(tot * (1.0f / (float)STATE_) + 1e-6f);
    const float4 w4 = ((const float4*)nw)[t];
    ushort4 o;
    o.x = bfbits(v.x * scale * w4.x);
    o.y = bfbits(v.y * scale * w4.y);
    o.z = bfbits(v.z * scale * w4.z);
    o.w = bfbits(v.w * scale * w4.w);
    ((ushort4*)out)[(size_t)row * (STATE_ / 4) + t] = o;
}

// ---------------------------------------------------------------- launcher
extern "C" void kernel_launch(void* const* d_in, const int* in_sizes, int n_in,
                              void* d_out, int out_size, void* d_ws, size_t ws_size,
                              hipStream_t stream) {
    const float* x      = (const float*)d_in[0];
    const float* w_in   = (const float*)d_in[1];
    const float* conv_w = (const float*)d_in[2];
    const float* sw     = (const float*)d_in[3];
    const float* norm_w = (const float*)d_in[4];
    const float* w_out  = (const float*)d_in[5];
    float* out = (float*)d_out;                    // (4,4096,1024) fp32 = 64 MiB

    // workspace layout (bytes):
    //   [0,        33554432)  xbf (bf16)      -- reused as y fp32 after GEMM1
    //   [33554432, 37748736)  w_inbf
    //   [37748736, 38797312)  w_outbf
    //   [38797312, 105906176) scanin (ushort4) -- reused as ybf after scan
    // projbf (16384x2048 bf16 = 64 MiB) lives in d_out until transpose_scan reads it.
    char* ws = (char*)d_ws;
    unsigned short* xbf     = (unsigned short*)(ws + 0);
    unsigned short* w_inbf  = (unsigned short*)(ws + 33554432);
    unsigned short* w_outbf = (unsigned short*)(ws + 37748736);
    ushort4*        scanin  = (ushort4*)(ws + 38797312);
    float*          yf      = (float*)(ws + 0);
    unsigned short* ybf     = (unsigned short*)(ws + 38797312);
    unsigned short* projbf  = (unsigned short*)d_out;   // scratch inside d_out

    // 1) fp32 -> bf16 converts
    f2bf<<<(ROWS_ * D_ / 4 + 255) / 256, 256, 0, stream>>>(x, xbf, ROWS_ * D_ / 4);
    f2bf<<<(PROJ_ * D_ / 4 + 255) / 256, 256, 0, stream>>>(w_in, w_inbf, PROJ_ * D_ / 4);
    f2bf<<<(D_ * STATE_ / 4 + 255) / 256, 256, 0, stream>>>(w_out, w_outbf, D_ * STATE_ / 4);

    // 2) proj = x @ w_in^T -> bf16 (into d_out scratch)
    gemm_bt<__hip_bfloat16><<<dim3(PROJ_ / 128, ROWS_ / 128), 256, 0, stream>>>(
        xbf, w_inbf, (__hip_bfloat16*)projbf, ROWS_, PROJ_, D_);

    // 3) rearrange proj for the scan (1 coalesced b64 load per step per lane)
    transpose_scan<<<ROWS_ * 512 / 256, 256, 0, stream>>>(projbf, scanin);

    // 4) recurrence (conv+silu+scan+silu(g) fused), writes y fp32
    //    32 blocks x 1 wave; LDS-broadcast matvecs (no readlanes)
    scan_kernel<<<32, 64, 0, stream>>>(scanin, conv_w, sw, yf);

    // 5) RMSNorm + bf16 cast
    rmsnorm_bf16<<<ROWS_, 128, 0, stream>>>(yf, norm_w, ybf);

    // 6) out = y_norm @ w_out^T (overwrites the projbf scratch)
    gemm_bt<float><<<dim3(D_ / 128, ROWS_ / 128), 256, 0, stream>>>(
        ybf, w_outbf, out, ROWS_, D_, STATE_);
}